// Round 12
// baseline (227.467 us; speedup 1.0000x reference)
//
#include <hip/hip_runtime.h>
#include <hip/hip_bf16.h>
#include <cstdint>
#include <cstddef>

typedef __bf16 bf16;
typedef __bf16 bf16x4 __attribute__((ext_vector_type(4)));
typedef __bf16 bf16x8 __attribute__((ext_vector_type(8)));
typedef float  f32x4  __attribute__((ext_vector_type(4)));
typedef float  f32x16 __attribute__((ext_vector_type(16)));

#define DEVINL __device__ __forceinline__

constexpr int   Bc  = 2, Sc = 2048, Hc = 1024, NHc = 16, HDc = 64;
constexpr int   Tc  = Bc * Sc;                 // 4096 tokens
constexpr float L2E = 1.44269504088896340736f;
constexpr float NEG_BIG = -1.0e30f;
constexpr float INV2PI = 0.15915494309189535f;

typedef __attribute__((address_space(1))) void AS1void;
typedef __attribute__((address_space(3))) void AS3void;

DEVINL void load_lds16(const bf16* g, bf16* l) {
  __builtin_amdgcn_global_load_lds((AS1void*)g, (AS3void*)l, 16, 0, 0);
}

// R23: guaranteed single-instruction exp2 (raw v_exp_f32). The __has_builtin
// guard could silently fall back to OCML exp2f (multi-instr + branches);
// inline asm removes that uncertainty. v_exp_f32(-1e30) = 0 handles masks.
DEVINL float fast_exp2(float x) {
  float r;
  asm("v_exp_f32 %0, %1" : "=v"(r) : "v"(x));
  return r;
}

#if __has_builtin(__builtin_amdgcn_sinf) && __has_builtin(__builtin_amdgcn_cosf) && __has_builtin(__builtin_amdgcn_fractf)
DEVINL void fast_sincos_rev(float rev, float* sn, float* cs) {
  float r = __builtin_amdgcn_fractf(rev);
  *sn = __builtin_amdgcn_sinf(r);
  *cs = __builtin_amdgcn_cosf(r);
}
#else
DEVINL void fast_sincos_rev(float rev, float* sn, float* cs) {
  sincosf(rev * 6.283185307179586f, sn, cs);
}
#endif

DEVINL f32x16 zero16() {
  f32x16 z;
#pragma unroll
  for (int i = 0; i < 16; i++) z[i] = 0.f;
  return z;
}

// R20: T1 bijective XCD-chunked swizzle (XCD = flat%8 [R11]); kept (R9 best).
DEVINL void xcd_remap(int& mi, int& ni) {
  const int nx  = (int)gridDim.x;
  const int nwg = nx * (int)gridDim.y;
  const int flat = (int)blockIdx.y * nx + (int)blockIdx.x;
  const int nper = nwg >> 3;
  const int neu  = (flat & 7) * nper + (flat >> 3);
  mi = neu / nx; ni = neu - mi * nx;
}

// ---------------------------------------------------------------------------
// Fused fp32->bf16 conversion of all inputs + bias pack, ONE dispatch.
// ---------------------------------------------------------------------------
__global__ __launch_bounds__(256)
void convert_all(const float* __restrict__ hs, const float* __restrict__ Wqkv,
                 const float* __restrict__ Wqa, const float* __restrict__ Wka,
                 const float* __restrict__ Wd, const float* __restrict__ bqa,
                 const float* __restrict__ bka,
                 bf16* __restrict__ hsb, bf16* __restrict__ wqkvb,
                 bf16* __restrict__ wqakab, bf16* __restrict__ wdb,
                 float* __restrict__ bqaka) {
  const int blk = blockIdx.x;
  if (blk >= 5120) {  // bias pack: 2048 floats
    const int i = threadIdx.x * 8;
    const float* src = (i < 1024) ? (bqa + i) : (bka + i - 1024);
    *(f32x4*)(bqaka + i)     = *(const f32x4*)src;
    *(f32x4*)(bqaka + i + 4) = *(const f32x4*)(src + 4);
    return;
  }
  const float* src; bf16* dst; int base;
  if      (blk < 2048) { src = hs;   dst = hsb;                    base = blk; }
  else if (blk < 3584) { src = Wqkv; dst = wqkvb;                  base = blk - 2048; }
  else if (blk < 4096) { src = Wqa;  dst = wqakab;                 base = blk - 3584; }
  else if (blk < 4608) { src = Wka;  dst = wqakab + 1024 * 1024;   base = blk - 4096; }
  else                 { src = Wd;   dst = wdb;                    base = blk - 4608; }
  const int i = (base * 256 + threadIdx.x) * 8;
  f32x4 a = *(const f32x4*)(src + i);
  f32x4 b = *(const f32x4*)(src + i + 4);
  bf16x8 v;
#pragma unroll
  for (int j = 0; j < 4; j++) { v[j] = (bf16)a[j]; v[4 + j] = (bf16)b[j]; }
  *(bf16x8*)(dst + i) = v;
}

// ---------------------------------------------------------------------------
// gemm128: 128x128 tile, BK=64, XOR-swizzled LDS, XCD-chunked remap (R20).
// ---------------------------------------------------------------------------
template <typename CT>
__global__ __launch_bounds__(256, 3)
void gemm128(const bf16* __restrict__ A, const bf16* __restrict__ Bw,
             const float* __restrict__ bias, CT* __restrict__ C,
             int M, int N, int K) {
  __shared__ __attribute__((aligned(16))) bf16 As[128 * 64];
  __shared__ __attribute__((aligned(16))) bf16 Bs[128 * 64];

  const int tid = threadIdx.x, wv = tid >> 6, lane = tid & 63;
  int mi, ni; xcd_remap(mi, ni);
  const int m0 = mi * 128, n0 = ni * 128;
  const int col = lane & 15, quad = lane >> 4;
  const int wrow = (wv >> 1) * 64, wcol = (wv & 1) * 64;

  f32x4 acc[4][4];
#pragma unroll
  for (int i = 0; i < 4; i++)
#pragma unroll
    for (int j = 0; j < 4; j++) acc[i][j] = f32x4{0.f, 0.f, 0.f, 0.f};

  const int srow = tid >> 3;
  const int scol = (((tid & 7) ^ (srow & 7)) << 3);
  const bf16* Ag = A  + (size_t)(m0 + srow) * K + scol;
  const bf16* Bg = Bw + (size_t)(n0 + srow) * K + scol;
  const int cs = col & 7;

  for (int k0 = 0; k0 < K; k0 += 64) {
#pragma unroll
    for (int c = 0; c < 4; c++) {
      load_lds16(Ag + (size_t)(c * 32) * K + k0, As + c * 2048 + tid * 8);
      load_lds16(Bg + (size_t)(c * 32) * K + k0, Bs + c * 2048 + tid * 8);
    }
    __syncthreads();
#pragma unroll
    for (int kk = 0; kk < 64; kk += 32) {
      const int so = ((((kk >> 3) + quad) ^ cs) << 3);
      bf16x8 af[4], bfr[4];
#pragma unroll
      for (int i = 0; i < 4; i++)
        af[i] = *(const bf16x8*)(As + (wrow + i * 16 + col) * 64 + so);
#pragma unroll
      for (int j = 0; j < 4; j++)
        bfr[j] = *(const bf16x8*)(Bs + (wcol + j * 16 + col) * 64 + so);
#pragma unroll
      for (int i = 0; i < 4; i++)
#pragma unroll
        for (int j = 0; j < 4; j++)
          acc[i][j] = __builtin_amdgcn_mfma_f32_16x16x32_bf16(af[i], bfr[j], acc[i][j], 0, 0, 0);
    }
    __syncthreads();
  }

#pragma unroll
  for (int j = 0; j < 4; j++) {
    const int c = n0 + wcol + j * 16 + col;
    const float bv = bias[c];
#pragma unroll
    for (int i = 0; i < 4; i++)
#pragma unroll
      for (int r = 0; r < 4; r++) {
        const int rr = m0 + wrow + i * 16 + quad * 4 + r;
        C[(size_t)rr * N + c] = (CT)(acc[i][j][r] + bv);
      }
  }
}

// ---------------------------------------------------------------------------
// gemm12864: 128x64 tile for the final projection. XCD-chunked remap (R20).
// ---------------------------------------------------------------------------
template <typename CT>
__global__ __launch_bounds__(256, 3)
void gemm12864(const bf16* __restrict__ A, const bf16* __restrict__ Bw,
               const float* __restrict__ bias, CT* __restrict__ C,
               int M, int N, int K) {
  __shared__ __attribute__((aligned(16))) bf16 As[128 * 64];
  __shared__ __attribute__((aligned(16))) bf16 Bs[64 * 64];

  const int tid = threadIdx.x, wv = tid >> 6, lane = tid & 63;
  int mi, ni; xcd_remap(mi, ni);
  const int m0 = mi * 128, n0 = ni * 64;
  const int col = lane & 15, quad = lane >> 4;
  const int wm = wv >> 1, wn = wv & 1;

  f32x4 acc[4][2];
#pragma unroll
  for (int i = 0; i < 4; i++)
#pragma unroll
    for (int j = 0; j < 2; j++) acc[i][j] = f32x4{0.f, 0.f, 0.f, 0.f};

  const int srow = tid >> 3;
  const int scol = (((tid & 7) ^ (srow & 7)) << 3);
  const bf16* Ag = A  + (size_t)(m0 + srow) * K + scol;
  const bf16* Bg = Bw + (size_t)(n0 + srow) * K + scol;
  const int cs = col & 7;

  for (int k0 = 0; k0 < K; k0 += 64) {
#pragma unroll
    for (int c = 0; c < 4; c++)
      load_lds16(Ag + (size_t)(c * 32) * K + k0, As + c * 2048 + tid * 8);
#pragma unroll
    for (int c = 0; c < 2; c++)
      load_lds16(Bg + (size_t)(c * 32) * K + k0, Bs + c * 2048 + tid * 8);
    __syncthreads();
#pragma unroll
    for (int kk = 0; kk < 64; kk += 32) {
      const int so = ((((kk >> 3) + quad) ^ cs) << 3);
      bf16x8 af[4], bfr[2];
#pragma unroll
      for (int i = 0; i < 4; i++)
        af[i] = *(const bf16x8*)(As + (wm * 64 + i * 16 + col) * 64 + so);
#pragma unroll
      for (int j = 0; j < 2; j++)
        bfr[j] = *(const bf16x8*)(Bs + (wn * 32 + j * 16 + col) * 64 + so);
#pragma unroll
      for (int i = 0; i < 4; i++)
#pragma unroll
        for (int j = 0; j < 2; j++)
          acc[i][j] = __builtin_amdgcn_mfma_f32_16x16x32_bf16(af[i], bfr[j], acc[i][j], 0, 0, 0);
    }
    __syncthreads();
  }

#pragma unroll
  for (int j = 0; j < 2; j++) {
    const int c = n0 + wn * 32 + j * 16 + col;
    const float bv = bias[c];
#pragma unroll
    for (int i = 0; i < 4; i++)
#pragma unroll
      for (int r = 0; r < 4; r++) {
        const int rr = m0 + wm * 64 + i * 16 + quad * 4 + r;
        C[(size_t)rr * N + c] = (CT)(acc[i][j][r] + bv);
      }
  }
}

// ---------------------------------------------------------------------------
// Sliding-window (W=16) attention with FUSED RoPE and FUSED V-transpose.
// R16: HW trig. R23: raw v_exp_f32 softmax exp.
// ---------------------------------------------------------------------------
__global__ __launch_bounds__(256)
void window_attn(const bf16* __restrict__ qkv, bf16* __restrict__ Ah,
                 bf16* __restrict__ VTg) {
  __shared__ __attribute__((aligned(16))) bf16 Kw[31 * 72];
  __shared__ __attribute__((aligned(16))) bf16 Vw[31 * 72];
  const int g  = blockIdx.x;
  const int st = g & 127;
  const int h  = (g >> 7) & 15;
  const int b  = g >> 11;
  const int s0 = st * 16;
  const int tid = threadIdx.x;

  if ((tid < 124) || (tid >= 128 && tid < 252)) {
    const bool isK = tid < 124;
    const int lt  = isK ? tid : tid - 128;
    const int r   = lt >> 2, off = (lt & 3) << 4;
    int sidx = s0 - 15 + r; if (sidx < 0) sidx = 0;
    const bf16* src = qkv + (size_t)(b * Sc + sidx) * 3072 + (isK ? 1024 : 2048) + h * 64 + off;
    bf16x8 v0 = *(const bf16x8*)src;
    bf16x8 v1 = *(const bf16x8*)(src + 8);
    if (isK && off == 0) {
#pragma unroll
      for (int j = 0; j < 8; j++) {
        const float invf_rev = exp2f(-(float)j * 1.66096404744368128f) * INV2PI;
        float sn, csn;
        fast_sincos_rev((float)sidx * invf_rev, &sn, &csn);
        const float x1 = (float)v0[j], x2 = (float)v1[j];
        v0[j] = (bf16)(x1 * csn - x2 * sn);
        v1[j] = (bf16)(x2 * csn + x1 * sn);
      }
    }
    bf16* dst = (isK ? Kw : Vw) + r * 72 + off;
    *(bf16x8*)dst       = v0;
    *(bf16x8*)(dst + 8) = v1;
  }
  __syncthreads();

  const int wv = tid >> 6, lane = tid & 63;
  const int subq = lane >> 4, lane16 = lane & 15;
  const int s = s0 + wv * 4 + subq;
  const int t = b * Sc + s;
  const int d0 = lane16 * 4;

  float qd[4];
  {
    bf16x4 qv = *(const bf16x4*)(qkv + (size_t)t * 3072 + h * 64 + d0);
#pragma unroll
    for (int j = 0; j < 4; j++) qd[j] = (float)qv[j];
  }
  float pd[4];
#pragma unroll
  for (int j = 0; j < 4; j++) pd[j] = __shfl_xor(qd[j], 2, 64);
  if (lane16 < 4) {
#pragma unroll
    for (int j = 0; j < 4; j++) {
      const int jabs = d0 + j;
      const float invf_rev = exp2f(-(float)(jabs & 7) * 1.66096404744368128f) * INV2PI;
      float sn, csn;
      fast_sincos_rev((float)s * invf_rev, &sn, &csn);
      qd[j] = (jabs < 8) ? (qd[j] * csn - pd[j] * sn) : (qd[j] * csn + pd[j] * sn);
    }
  }

  float sc[16];
#pragma unroll
  for (int w = 0; w < 16; w++) {
    const int idxp = s - 15 + w;
    const int row = idxp - s0 + 15;
    bf16x4 kv = *(const bf16x4*)(Kw + row * 72 + d0);
    float p = qd[0] * (float)kv[0] + qd[1] * (float)kv[1] +
              qd[2] * (float)kv[2] + qd[3] * (float)kv[3];
#pragma unroll
    for (int m = 1; m < 16; m <<= 1) p += __shfl_xor(p, m, 64);
    sc[w] = (idxp < 0) ? NEG_BIG : p * 0.125f;
  }
  float mx = sc[0];
#pragma unroll
  for (int w = 1; w < 16; w++) mx = fmaxf(mx, sc[w]);
  float sum = 0.f;
#pragma unroll
  for (int w = 0; w < 16; w++) { sc[w] = fast_exp2((sc[w] - mx) * L2E); sum += sc[w]; }
  const float inv = 1.0f / fmaxf(sum, 1e-30f);

  float acc[4] = {0.f, 0.f, 0.f, 0.f};
#pragma unroll
  for (int w = 0; w < 16; w++) {
    const int idxp = s - 15 + w;
    const int row = idxp - s0 + 15;
    bf16x4 vv = *(const bf16x4*)(Vw + row * 72 + d0);
#pragma unroll
    for (int j = 0; j < 4; j++) acc[j] += sc[w] * (float)vv[j];
  }
  bf16x4 ov;
#pragma unroll
  for (int j = 0; j < 4; j++) ov[j] = (bf16)(acc[j] * inv);
  *(bf16x4*)(Ah + (size_t)t * 1024 + h * 64 + d0) = ov;
  bf16* vt = VTg + (((size_t)(b * 16 + h)) * 64 + d0) * 2048 + s;
#pragma unroll
  for (int j = 0; j < 4; j++) vt[(size_t)j * 2048] = ov[j];
}

// ---------------------------------------------------------------------------
// Dense causal flash attention — R22 structure (verified) + R23 VALU polish.
//
// 32x32x16 fragments; triple-buffered 32 KB tiles, depth-2 prefetch, counted
// vmcnt (never 0 mid-loop), one barrier/tile; q=128/block, 17 balanced tiles;
// T12 in-register softmax (swapped QK^T, 4 cvt_pk + 2 permlane32_swap);
// 4-phase exact-fit cross-kw combine through dead bufc LDS.
// R23: raw v_exp_f32 (removes possible OCML fallback), lsum split into two
// accumulators (halves the serial add chain).
// ---------------------------------------------------------------------------
__global__ __launch_bounds__(512, 1)
void flash_attn(const bf16* __restrict__ Q, const bf16* __restrict__ Kt,
                const bf16* __restrict__ VTg, bf16* __restrict__ O) {
  constexpr int QS = 2048;
  __shared__ __attribute__((aligned(16))) bf16 K_lds[3][128 * 64];
  __shared__ __attribute__((aligned(16))) bf16 VT_lds[3][64 * 128];

  const int tid = threadIdx.x, wv = tid >> 6, lane = tid & 63;
  const int qw = wv >> 1, kw = wv & 1;
  const int bh = blockIdx.x;            // 0..31  (XCD = bh % 8)
  const int y  = blockIdx.y;            // 0..7
  const int qtA = y, qtB = 15 - y;      // 128-row q-tile ids
  const int nA = y + 1;                 // tiles in segment A; nA + nB == 17
  const int b = bh >> 4, h = bh & 15;
  const size_t bS = (size_t)b * Sc;
  const int hd = h * 64;
  const int l31 = lane & 31, lhi = lane >> 5, l15 = lane & 15, l7 = lane & 7;

  // staging (identical to R15)
  const int krow = tid >> 3;
  const int kswz = (((tid & 7) ^ (krow & 7)) << 3);
  const int vrow = tid >> 4;
  const int vswz = (((tid & 15) ^ (vrow & 15)) << 3);
  const bf16* Kg0 = Kt  + (bS * QS) + (size_t)krow * QS + hd + kswz;
  const bf16* Vg0 = VTg + ((size_t)bh * 64 + vrow) * 2048 + vswz;

  // Q B-fragments: lane holds Q[d = dc*16 + 8*lhi + j][q = qbase + l31].
  bf16x8 qA0, qA1, qA2, qA3, qB0, qB1, qB2, qB3;
  {
    constexpr float QSC = 0.125f * L2E;
    const bf16* pA = Q + (bS + qtA * 128 + qw * 32 + l31) * QS + hd + lhi * 8;
    const bf16* pB = Q + (bS + qtB * 128 + qw * 32 + l31) * QS + hd + lhi * 8;
    qA0 = *(const bf16x8*)(pA);      qA1 = *(const bf16x8*)(pA + 16);
    qA2 = *(const bf16x8*)(pA + 32); qA3 = *(const bf16x8*)(pA + 48);
    qB0 = *(const bf16x8*)(pB);      qB1 = *(const bf16x8*)(pB + 16);
    qB2 = *(const bf16x8*)(pB + 32); qB3 = *(const bf16x8*)(pB + 48);
#pragma unroll
    for (int j = 0; j < 8; j++) {
      qA0[j] = (bf16)((float)qA0[j] * QSC); qA1[j] = (bf16)((float)qA1[j] * QSC);
      qA2[j] = (bf16)((float)qA2[j] * QSC); qA3[j] = (bf16)((float)qA3[j] * QSC);
      qB0[j] = (bf16)((float)qB0[j] * QSC); qB1[j] = (bf16)((float)qB1[j] * QSC);
      qB2[j] = (bf16)((float)qB2[j] * QSC); qB3[j] = (bf16)((float)qB3[j] * QSC);
    }
  }

  auto stage = [&](int bufi, int k0) {
    const bf16* kg = Kg0 + (size_t)k0 * QS;
    const bf16* vg = Vg0 + k0;
#pragma unroll
    for (int c = 0; c < 2; c++) {
      load_lds16(kg + (size_t)(c * 64) * QS, K_lds[bufi] + c * 4096 + tid * 8);
      load_lds16(vg + (size_t)(c * 32) * 2048, VT_lds[bufi] + c * 4096 + tid * 8);
    }
  };
  auto k0of = [&](int i) { return ((i >= nA) ? i - nA : i) * 128; };

  f32x16 oacc0 = zero16(), oacc1 = zero16();
  float lsum0 = 0.f, lsum1 = 0.f;

  stage(0, 0);
  stage(1, k0of(1));

  for (int it = 0; it < 17; it++) {
    const int seg  = (it >= nA);
    const int kt   = seg ? (it - nA) : it;
    const int nkt  = seg ? (17 - nA) : nA;
    const int qt   = seg ? qtB : qtA;
    const int k0   = kt * 128;
    const int qbase = qt * 128 + qw * 32;
    const int bufc = it % 3;

    if (it == 16)                      asm volatile("s_waitcnt vmcnt(0)" ::: "memory");
    else if (it == nA || it == nA + 1) asm volatile("s_waitcnt vmcnt(8)" ::: "memory");
    else                               asm volatile("s_waitcnt vmcnt(4)" ::: "memory");
    __builtin_amdgcn_s_barrier();
    __builtin_amdgcn_sched_barrier(0);

    if (it + 2 < 17) stage((it + 2) % 3, k0of(it + 2));

    bf16x8 q0, q1, q2, q3;
    if (seg) { q0 = qB0; q1 = qB1; q2 = qB2; q3 = qB3; }
    else     { q0 = qA0; q1 = qA1; q2 = qA2; q3 = qA3; }

    const bf16* Kl = K_lds[bufc];
    const bf16* Vl = VT_lds[bufc];

    // QK^T: S^T for this wave's two 32-key blocks (kw half).
    f32x16 s0_ = zero16(), s1_ = zero16();
    __builtin_amdgcn_s_setprio(1);
    {
      const int kr0 = ((kw * 2 + 0) * 32 + l31) * 64;
      const int kr1 = ((kw * 2 + 1) * 32 + l31) * 64;
#pragma unroll
      for (int dc = 0; dc < 4; dc++) {
        const int so = (((2 * dc + lhi) ^ l7) << 3);
        bf16x8 qf = (dc == 0) ? q0 : (dc == 1) ? q1 : (dc == 2) ? q2 : q3;
        bf16x8 kf0 = *(const bf16x8*)(Kl + kr0 + so);
        s0_ = __builtin_amdgcn_mfma_f32_32x32x16_bf16(kf0, qf, s0_, 0, 0, 0);
        bf16x8 kf1 = *(const bf16x8*)(Kl + kr1 + so);
        s1_ = __builtin_amdgcn_mfma_f32_32x32x16_bf16(kf1, qf, s1_, 0, 0, 0);
      }
    }
    __builtin_amdgcn_s_setprio(0);

    if (kt == nkt - 1) {
      const int qq = qbase + l31;
      const int kb0 = k0 + kw * 64;
#pragma unroll
      for (int r = 0; r < 16; r++) {
        const int ky = kb0 + (r & 3) + 8 * (r >> 2) + 4 * lhi;
        if (ky > qq)      s0_[r] = NEG_BIG;
        if (ky + 32 > qq) s1_[r] = NEG_BIG;
      }
    }
#pragma unroll
    for (int r = 0; r < 16; r++) {
      const float p0 = fast_exp2(s0_[r]); s0_[r] = p0; lsum0 += p0;
      const float p1 = fast_exp2(s1_[r]); s1_[r] = p1; lsum1 += p1;
    }

    // PV: per (kb, f) 16-key B-frag -> 2 MFMAs (d-blocks).
#define PV_STEP(SACC, KB, F)                                                   \
    {                                                                          \
      uint32_t a0, a1, b0, b1;                                                 \
      asm("v_cvt_pk_bf16_f32 %0, %1, %2" : "=v"(a0)                            \
          : "v"(SACC[(F)*8 + 0]), "v"(SACC[(F)*8 + 1]));                       \
      asm("v_cvt_pk_bf16_f32 %0, %1, %2" : "=v"(a1)                            \
          : "v"(SACC[(F)*8 + 2]), "v"(SACC[(F)*8 + 3]));                       \
      asm("v_cvt_pk_bf16_f32 %0, %1, %2" : "=v"(b0)                            \
          : "v"(SACC[(F)*8 + 4]), "v"(SACC[(F)*8 + 5]));                       \
      asm("v_cvt_pk_bf16_f32 %0, %1, %2" : "=v"(b1)                            \
          : "v"(SACC[(F)*8 + 6]), "v"(SACC[(F)*8 + 7]));                       \
      asm("v_permlane32_swap_b32 %0, %1" : "+v"(a0), "+v"(b0));                \
      asm("v_permlane32_swap_b32 %0, %1" : "+v"(a1), "+v"(b1));                \
      union { uint32_t u[4]; bf16x8 v; } pk;                                   \
      pk.u[0] = a0; pk.u[1] = a1; pk.u[2] = b0; pk.u[3] = b1;                  \
      const int kc = kw * 8 + (KB) * 4 + (F) * 2;                              \
      const int vso = (((kc + lhi) ^ l15) << 3);                               \
      __builtin_amdgcn_s_setprio(1);                                           \
      { bf16x8 vf = *(const bf16x8*)(Vl + (l31) * 128 + vso);                  \
        oacc0 = __builtin_amdgcn_mfma_f32_32x32x16_bf16(vf, pk.v, oacc0, 0, 0, 0); } \
      { bf16x8 vf = *(const bf16x8*)(Vl + (32 + l31) * 128 + vso);             \
        oacc1 = __builtin_amdgcn_mfma_f32_32x32x16_bf16(vf, pk.v, oacc1, 0, 0, 0); } \
      __builtin_amdgcn_s_setprio(0);                                           \
    }
    PV_STEP(s0_, 0, 0)
    PV_STEP(s0_, 0, 1)
    PV_STEP(s1_, 1, 0)
    PV_STEP(s1_, 1, 1)
#undef PV_STEP

    // segment finalize: 4-phase exact-fit cross-kw combine via dead bufc LDS
    if (kt == nkt - 1) {
      const float lsum = lsum0 + lsum1;
      float totw = lsum + __shfl_xor(lsum, 32, 64);
      asm volatile("s_waitcnt lgkmcnt(0)" ::: "memory");
      __builtin_amdgcn_s_barrier();           // all bufc reads complete
      float* Kf = (float*)(&K_lds[bufc][0]);  // 4096 floats (dead)
      float* Vf = (float*)(&VT_lds[bufc][0]); // 4096 floats (dead)
      float* slot = Kf + qw * 1024 + (lane << 4);
      // P1: kw=1 publishes oacc0; both publish tot
      if (lhi == 0) Vf[kw * 128 + qw * 32 + l31] = totw;
      if (kw == 1) {
#pragma unroll
        for (int g = 0; g < 4; g++)
          *(f32x4*)(slot + 4 * g) = f32x4{oacc0[4 * g], oacc0[4 * g + 1],
                                          oacc0[4 * g + 2], oacc0[4 * g + 3]};
      }
      asm volatile("s_waitcnt lgkmcnt(0)" ::: "memory");
      __builtin_amdgcn_s_barrier();
      __builtin_amdgcn_sched_barrier(0);
      const int q = qbase + l31;
      bf16* Op = O + (bS + q) * 1024 + hd + kw * 32 + 4 * lhi;
      const float ptot = Vf[(kw ^ 1) * 128 + qw * 32 + l31];
      const float inv = 1.0f / fmaxf(totw + ptot, 1e-37f);
      // P2: kw=0 combines oacc0, stores O rows d 0..31
      if (kw == 0) {
#pragma unroll
        for (int g = 0; g < 4; g++) {
          f32x4 po = *(const f32x4*)(slot + 4 * g);
          bf16x4 ov;
#pragma unroll
          for (int j = 0; j < 4; j++)
            ov[j] = (bf16)((oacc0[4 * g + j] + po[j]) * inv);
          *(bf16x4*)(Op + 8 * g) = ov;
        }
      }
      asm volatile("s_waitcnt lgkmcnt(0)" ::: "memory");
      __builtin_amdgcn_s_barrier();           // P2 reads done before overwrite
      // P3: kw=0 publishes oacc1 into the same slots
      if (kw == 0) {
#pragma unroll
        for (int g = 0; g < 4; g++)
          *(f32x4*)(slot + 4 * g) = f32x4{oacc1[4 * g], oacc1[4 * g + 1],
                                          oacc1[4 * g + 2], oacc1[4 * g + 3]};
      }
      asm volatile("s_waitcnt lgkmcnt(0)" ::: "memory");
      __builtin_amdgcn_s_barrier();
      __builtin_amdgcn_sched_barrier(0);
      // P4: kw=1 combines oacc1, stores O rows d 32..63
      if (kw == 1) {
#pragma unroll
        for (int g = 0; g < 4; g++) {
          f32x4 po = *(const f32x4*)(slot + 4 * g);
          bf16x4 ov;
#pragma unroll
          for (int j = 0; j < 4; j++)
            ov[j] = (bf16)((oacc1[4 * g + j] + po[j]) * inv);
          *(bf16x4*)(Op + 8 * g) = ov;
        }
      }
      oacc0 = zero16(); oacc1 = zero16();
      lsum0 = 0.f; lsum1 = 0.f;
    }
  }
}

// ---------------------------------------------------------------------------
extern "C" void kernel_launch(void* const* d_in, const int* in_sizes, int n_in,
                              void* d_out, int out_size, void* d_ws, size_t ws_size,
                              hipStream_t stream) {
  (void)in_sizes; (void)n_in; (void)out_size; (void)ws_size;
  const float* hs   = (const float*)d_in[0];
  const float* Wqkv = (const float*)d_in[1];
  const float* bqkv = (const float*)d_in[2];
  const float* Wqa  = (const float*)d_in[3];
  const float* bqa  = (const float*)d_in[4];
  const float* Wka  = (const float*)d_in[5];
  const float* bka  = (const float*)d_in[6];
  const float* Wd   = (const float*)d_in[7];
  const float* bd   = (const float*)d_in[8];
  float* out = (float*)d_out;

  const size_t TH = (size_t)Tc * Hc;            // 4,194,304
  bf16* dob   = (bf16*)d_out;
  bf16* hsb   = dob;
  bf16* wqkvb = dob + TH;
  bf16* Ah    = dob;
  bf16* VTg   = dob + TH;
  bf16* ws     = (bf16*)d_ws;
  bf16* qkv    = ws;
  bf16* qaka   = ws;
  bf16* oh     = ws + 2 * TH;
  bf16* wqakab = ws + 3 * TH;
  bf16* wdb    = wqakab + 2 * 1024 * 1024;
  float* bqaka = (float*)(wdb + 1024 * 1024);

  convert_all<<<dim3(5121), 256, 0, stream>>>(hs, Wqkv, Wqa, Wka, Wd, bqa, bka,
                                              hsb, wqkvb, wqakab, wdb, bqaka);

  gemm128<bf16><<<dim3(24, 32), 256, 0, stream>>>(hsb, wqkvb, bqkv, qkv, Tc, 3 * Hc, Hc);
  window_attn<<<dim3(Tc * NHc / 16), 256, 0, stream>>>(qkv, Ah, VTg);
  gemm128<bf16><<<dim3(16, 32), 256, 0, stream>>>(Ah, wqakab, bqaka, qaka, Tc, 2 * Hc, Hc);
  // flash: 256 blocks x 512 thr, q=128/block, 17 tiles, 32x32 frags (R22/R23)
  flash_attn<<<dim3(Bc * NHc, 8), 512, 0, stream>>>(qaka, qaka + Hc, VTg, oh);
  // final projection: 128x64 tiles, 512 blocks = 2/CU
  gemm12864<float><<<dim3(16, 32), 256, 0, stream>>>(oh, wdb, bd, out, Tc, Hc, Hc);
}

// Round 13
// 218.053 us; speedup vs baseline: 1.0432x; 1.0432x over previous
//
#include <hip/hip_runtime.h>
#include <hip/hip_bf16.h>
#include <cstdint>
#include <cstddef>

typedef __bf16 bf16;
typedef __bf16 bf16x4 __attribute__((ext_vector_type(4)));
typedef __bf16 bf16x8 __attribute__((ext_vector_type(8)));
typedef float  f32x4  __attribute__((ext_vector_type(4)));
typedef float  f32x16 __attribute__((ext_vector_type(16)));

#define DEVINL __device__ __forceinline__

constexpr int   Bc  = 2, Sc = 2048, Hc = 1024, NHc = 16, HDc = 64;
constexpr int   Tc  = Bc * Sc;                 // 4096 tokens
constexpr float L2E = 1.44269504088896340736f;
constexpr float NEG_BIG = -1.0e30f;
constexpr float INV2PI = 0.15915494309189535f;

typedef __attribute__((address_space(1))) void AS1void;
typedef __attribute__((address_space(3))) void AS3void;

DEVINL void load_lds16(const bf16* g, bf16* l) {
  __builtin_amdgcn_global_load_lds((AS1void*)g, (AS3void*)l, 16, 0, 0);
}

// R24: R23's inline-asm v_exp_f32 REVERTED (-9us: opaque asm blocks defeat
// compiler scheduling, exactly the m240 cvt_pk lesson). Builtin path is
// already single-instruction AND schedulable.
#if __has_builtin(__builtin_amdgcn_exp2f)
DEVINL float fast_exp2(float x) { return __builtin_amdgcn_exp2f(x); }
#else
DEVINL float fast_exp2(float x) { return exp2f(x); }
#endif

#if __has_builtin(__builtin_amdgcn_sinf) && __has_builtin(__builtin_amdgcn_cosf) && __has_builtin(__builtin_amdgcn_fractf)
DEVINL void fast_sincos_rev(float rev, float* sn, float* cs) {
  float r = __builtin_amdgcn_fractf(rev);
  *sn = __builtin_amdgcn_sinf(r);
  *cs = __builtin_amdgcn_cosf(r);
}
#else
DEVINL void fast_sincos_rev(float rev, float* sn, float* cs) {
  sincosf(rev * 6.283185307179586f, sn, cs);
}
#endif

DEVINL f32x16 zero16() {
  f32x16 z;
#pragma unroll
  for (int i = 0; i < 16; i++) z[i] = 0.f;
  return z;
}

// R20: T1 bijective XCD-chunked swizzle (XCD = flat%8 [R11]); kept (R9 best).
DEVINL void xcd_remap(int& mi, int& ni) {
  const int nx  = (int)gridDim.x;
  const int nwg = nx * (int)gridDim.y;
  const int flat = (int)blockIdx.y * nx + (int)blockIdx.x;
  const int nper = nwg >> 3;
  const int neu  = (flat & 7) * nper + (flat >> 3);
  mi = neu / nx; ni = neu - mi * nx;
}

// ---------------------------------------------------------------------------
// Fused fp32->bf16 conversion of all inputs + bias pack, ONE dispatch.
// ---------------------------------------------------------------------------
__global__ __launch_bounds__(256)
void convert_all(const float* __restrict__ hs, const float* __restrict__ Wqkv,
                 const float* __restrict__ Wqa, const float* __restrict__ Wka,
                 const float* __restrict__ Wd, const float* __restrict__ bqa,
                 const float* __restrict__ bka,
                 bf16* __restrict__ hsb, bf16* __restrict__ wqkvb,
                 bf16* __restrict__ wqakab, bf16* __restrict__ wdb,
                 float* __restrict__ bqaka) {
  const int blk = blockIdx.x;
  if (blk >= 5120) {  // bias pack: 2048 floats
    const int i = threadIdx.x * 8;
    const float* src = (i < 1024) ? (bqa + i) : (bka + i - 1024);
    *(f32x4*)(bqaka + i)     = *(const f32x4*)src;
    *(f32x4*)(bqaka + i + 4) = *(const f32x4*)(src + 4);
    return;
  }
  const float* src; bf16* dst; int base;
  if      (blk < 2048) { src = hs;   dst = hsb;                    base = blk; }
  else if (blk < 3584) { src = Wqkv; dst = wqkvb;                  base = blk - 2048; }
  else if (blk < 4096) { src = Wqa;  dst = wqakab;                 base = blk - 3584; }
  else if (blk < 4608) { src = Wka;  dst = wqakab + 1024 * 1024;   base = blk - 4096; }
  else                 { src = Wd;   dst = wdb;                    base = blk - 4608; }
  const int i = (base * 256 + threadIdx.x) * 8;
  f32x4 a = *(const f32x4*)(src + i);
  f32x4 b = *(const f32x4*)(src + i + 4);
  bf16x8 v;
#pragma unroll
  for (int j = 0; j < 4; j++) { v[j] = (bf16)a[j]; v[4 + j] = (bf16)b[j]; }
  *(bf16x8*)(dst + i) = v;
}

// ---------------------------------------------------------------------------
// gemm128: 128x128 tile, BK=64, XOR-swizzled LDS, XCD-chunked remap (R20).
// ---------------------------------------------------------------------------
template <typename CT>
__global__ __launch_bounds__(256, 3)
void gemm128(const bf16* __restrict__ A, const bf16* __restrict__ Bw,
             const float* __restrict__ bias, CT* __restrict__ C,
             int M, int N, int K) {
  __shared__ __attribute__((aligned(16))) bf16 As[128 * 64];
  __shared__ __attribute__((aligned(16))) bf16 Bs[128 * 64];

  const int tid = threadIdx.x, wv = tid >> 6, lane = tid & 63;
  int mi, ni; xcd_remap(mi, ni);
  const int m0 = mi * 128, n0 = ni * 128;
  const int col = lane & 15, quad = lane >> 4;
  const int wrow = (wv >> 1) * 64, wcol = (wv & 1) * 64;

  f32x4 acc[4][4];
#pragma unroll
  for (int i = 0; i < 4; i++)
#pragma unroll
    for (int j = 0; j < 4; j++) acc[i][j] = f32x4{0.f, 0.f, 0.f, 0.f};

  const int srow = tid >> 3;
  const int scol = (((tid & 7) ^ (srow & 7)) << 3);
  const bf16* Ag = A  + (size_t)(m0 + srow) * K + scol;
  const bf16* Bg = Bw + (size_t)(n0 + srow) * K + scol;
  const int cs = col & 7;

  for (int k0 = 0; k0 < K; k0 += 64) {
#pragma unroll
    for (int c = 0; c < 4; c++) {
      load_lds16(Ag + (size_t)(c * 32) * K + k0, As + c * 2048 + tid * 8);
      load_lds16(Bg + (size_t)(c * 32) * K + k0, Bs + c * 2048 + tid * 8);
    }
    __syncthreads();
#pragma unroll
    for (int kk = 0; kk < 64; kk += 32) {
      const int so = ((((kk >> 3) + quad) ^ cs) << 3);
      bf16x8 af[4], bfr[4];
#pragma unroll
      for (int i = 0; i < 4; i++)
        af[i] = *(const bf16x8*)(As + (wrow + i * 16 + col) * 64 + so);
#pragma unroll
      for (int j = 0; j < 4; j++)
        bfr[j] = *(const bf16x8*)(Bs + (wcol + j * 16 + col) * 64 + so);
#pragma unroll
      for (int i = 0; i < 4; i++)
#pragma unroll
        for (int j = 0; j < 4; j++)
          acc[i][j] = __builtin_amdgcn_mfma_f32_16x16x32_bf16(af[i], bfr[j], acc[i][j], 0, 0, 0);
    }
    __syncthreads();
  }

#pragma unroll
  for (int j = 0; j < 4; j++) {
    const int c = n0 + wcol + j * 16 + col;
    const float bv = bias[c];
#pragma unroll
    for (int i = 0; i < 4; i++)
#pragma unroll
      for (int r = 0; r < 4; r++) {
        const int rr = m0 + wrow + i * 16 + quad * 4 + r;
        C[(size_t)rr * N + c] = (CT)(acc[i][j][r] + bv);
      }
  }
}

// ---------------------------------------------------------------------------
// gemm12864: 128x64 tile for the final projection. XCD-chunked remap (R20).
// ---------------------------------------------------------------------------
template <typename CT>
__global__ __launch_bounds__(256, 3)
void gemm12864(const bf16* __restrict__ A, const bf16* __restrict__ Bw,
               const float* __restrict__ bias, CT* __restrict__ C,
               int M, int N, int K) {
  __shared__ __attribute__((aligned(16))) bf16 As[128 * 64];
  __shared__ __attribute__((aligned(16))) bf16 Bs[64 * 64];

  const int tid = threadIdx.x, wv = tid >> 6, lane = tid & 63;
  int mi, ni; xcd_remap(mi, ni);
  const int m0 = mi * 128, n0 = ni * 64;
  const int col = lane & 15, quad = lane >> 4;
  const int wm = wv >> 1, wn = wv & 1;

  f32x4 acc[4][2];
#pragma unroll
  for (int i = 0; i < 4; i++)
#pragma unroll
    for (int j = 0; j < 2; j++) acc[i][j] = f32x4{0.f, 0.f, 0.f, 0.f};

  const int srow = tid >> 3;
  const int scol = (((tid & 7) ^ (srow & 7)) << 3);
  const bf16* Ag = A  + (size_t)(m0 + srow) * K + scol;
  const bf16* Bg = Bw + (size_t)(n0 + srow) * K + scol;
  const int cs = col & 7;

  for (int k0 = 0; k0 < K; k0 += 64) {
#pragma unroll
    for (int c = 0; c < 4; c++)
      load_lds16(Ag + (size_t)(c * 32) * K + k0, As + c * 2048 + tid * 8);
#pragma unroll
    for (int c = 0; c < 2; c++)
      load_lds16(Bg + (size_t)(c * 32) * K + k0, Bs + c * 2048 + tid * 8);
    __syncthreads();
#pragma unroll
    for (int kk = 0; kk < 64; kk += 32) {
      const int so = ((((kk >> 3) + quad) ^ cs) << 3);
      bf16x8 af[4], bfr[2];
#pragma unroll
      for (int i = 0; i < 4; i++)
        af[i] = *(const bf16x8*)(As + (wm * 64 + i * 16 + col) * 64 + so);
#pragma unroll
      for (int j = 0; j < 2; j++)
        bfr[j] = *(const bf16x8*)(Bs + (wn * 32 + j * 16 + col) * 64 + so);
#pragma unroll
      for (int i = 0; i < 4; i++)
#pragma unroll
        for (int j = 0; j < 2; j++)
          acc[i][j] = __builtin_amdgcn_mfma_f32_16x16x32_bf16(af[i], bfr[j], acc[i][j], 0, 0, 0);
    }
    __syncthreads();
  }

#pragma unroll
  for (int j = 0; j < 2; j++) {
    const int c = n0 + wn * 32 + j * 16 + col;
    const float bv = bias[c];
#pragma unroll
    for (int i = 0; i < 4; i++)
#pragma unroll
      for (int r = 0; r < 4; r++) {
        const int rr = m0 + wm * 64 + i * 16 + quad * 4 + r;
        C[(size_t)rr * N + c] = (CT)(acc[i][j][r] + bv);
      }
  }
}

// ---------------------------------------------------------------------------
// Sliding-window (W=16) attention with FUSED RoPE and FUSED V-transpose.
// R16: HW trig (revolutions + fract). VT scatter kept (R18 bounce reverted).
// ---------------------------------------------------------------------------
__global__ __launch_bounds__(256)
void window_attn(const bf16* __restrict__ qkv, bf16* __restrict__ Ah,
                 bf16* __restrict__ VTg) {
  __shared__ __attribute__((aligned(16))) bf16 Kw[31 * 72];
  __shared__ __attribute__((aligned(16))) bf16 Vw[31 * 72];
  const int g  = blockIdx.x;
  const int st = g & 127;
  const int h  = (g >> 7) & 15;
  const int b  = g >> 11;
  const int s0 = st * 16;
  const int tid = threadIdx.x;

  if ((tid < 124) || (tid >= 128 && tid < 252)) {
    const bool isK = tid < 124;
    const int lt  = isK ? tid : tid - 128;
    const int r   = lt >> 2, off = (lt & 3) << 4;
    int sidx = s0 - 15 + r; if (sidx < 0) sidx = 0;
    const bf16* src = qkv + (size_t)(b * Sc + sidx) * 3072 + (isK ? 1024 : 2048) + h * 64 + off;
    bf16x8 v0 = *(const bf16x8*)src;
    bf16x8 v1 = *(const bf16x8*)(src + 8);
    if (isK && off == 0) {
#pragma unroll
      for (int j = 0; j < 8; j++) {
        const float invf_rev = exp2f(-(float)j * 1.66096404744368128f) * INV2PI;
        float sn, csn;
        fast_sincos_rev((float)sidx * invf_rev, &sn, &csn);
        const float x1 = (float)v0[j], x2 = (float)v1[j];
        v0[j] = (bf16)(x1 * csn - x2 * sn);
        v1[j] = (bf16)(x2 * csn + x1 * sn);
      }
    }
    bf16* dst = (isK ? Kw : Vw) + r * 72 + off;
    *(bf16x8*)dst       = v0;
    *(bf16x8*)(dst + 8) = v1;
  }
  __syncthreads();

  const int wv = tid >> 6, lane = tid & 63;
  const int subq = lane >> 4, lane16 = lane & 15;
  const int s = s0 + wv * 4 + subq;
  const int t = b * Sc + s;
  const int d0 = lane16 * 4;

  float qd[4];
  {
    bf16x4 qv = *(const bf16x4*)(qkv + (size_t)t * 3072 + h * 64 + d0);
#pragma unroll
    for (int j = 0; j < 4; j++) qd[j] = (float)qv[j];
  }
  float pd[4];
#pragma unroll
  for (int j = 0; j < 4; j++) pd[j] = __shfl_xor(qd[j], 2, 64);
  if (lane16 < 4) {
#pragma unroll
    for (int j = 0; j < 4; j++) {
      const int jabs = d0 + j;
      const float invf_rev = exp2f(-(float)(jabs & 7) * 1.66096404744368128f) * INV2PI;
      float sn, csn;
      fast_sincos_rev((float)s * invf_rev, &sn, &csn);
      qd[j] = (jabs < 8) ? (qd[j] * csn - pd[j] * sn) : (qd[j] * csn + pd[j] * sn);
    }
  }

  float sc[16];
#pragma unroll
  for (int w = 0; w < 16; w++) {
    const int idxp = s - 15 + w;
    const int row = idxp - s0 + 15;
    bf16x4 kv = *(const bf16x4*)(Kw + row * 72 + d0);
    float p = qd[0] * (float)kv[0] + qd[1] * (float)kv[1] +
              qd[2] * (float)kv[2] + qd[3] * (float)kv[3];
#pragma unroll
    for (int m = 1; m < 16; m <<= 1) p += __shfl_xor(p, m, 64);
    sc[w] = (idxp < 0) ? NEG_BIG : p * 0.125f;
  }
  float mx = sc[0];
#pragma unroll
  for (int w = 1; w < 16; w++) mx = fmaxf(mx, sc[w]);
  float sum = 0.f;
#pragma unroll
  for (int w = 0; w < 16; w++) { sc[w] = fast_exp2((sc[w] - mx) * L2E); sum += sc[w]; }
  const float inv = 1.0f / fmaxf(sum, 1e-30f);

  float acc[4] = {0.f, 0.f, 0.f, 0.f};
#pragma unroll
  for (int w = 0; w < 16; w++) {
    const int idxp = s - 15 + w;
    const int row = idxp - s0 + 15;
    bf16x4 vv = *(const bf16x4*)(Vw + row * 72 + d0);
#pragma unroll
    for (int j = 0; j < 4; j++) acc[j] += sc[w] * (float)vv[j];
  }
  bf16x4 ov;
#pragma unroll
  for (int j = 0; j < 4; j++) ov[j] = (bf16)(acc[j] * inv);
  *(bf16x4*)(Ah + (size_t)t * 1024 + h * 64 + d0) = ov;
  bf16* vt = VTg + (((size_t)(b * 16 + h)) * 64 + d0) * 2048 + s;
#pragma unroll
  for (int j = 0; j < 4; j++) vt[(size_t)j * 2048] = ov[j];
}

// ---------------------------------------------------------------------------
// Dense causal flash attention — R22 configuration (measured best, 218.5us).
//
// 32x32x16 fragments; triple-buffered 32 KB tiles, depth-2 prefetch, counted
// vmcnt (never 0 mid-loop), one barrier/tile; q=128/block, 17 balanced tiles;
// T12 in-register softmax (swapped QK^T, 4 cvt_pk + 2 permlane32_swap);
// 4-phase exact-fit cross-kw combine through dead bufc LDS.
// ---------------------------------------------------------------------------
__global__ __launch_bounds__(512, 1)
void flash_attn(const bf16* __restrict__ Q, const bf16* __restrict__ Kt,
                const bf16* __restrict__ VTg, bf16* __restrict__ O) {
  constexpr int QS = 2048;
  __shared__ __attribute__((aligned(16))) bf16 K_lds[3][128 * 64];
  __shared__ __attribute__((aligned(16))) bf16 VT_lds[3][64 * 128];

  const int tid = threadIdx.x, wv = tid >> 6, lane = tid & 63;
  const int qw = wv >> 1, kw = wv & 1;
  const int bh = blockIdx.x;            // 0..31  (XCD = bh % 8)
  const int y  = blockIdx.y;            // 0..7
  const int qtA = y, qtB = 15 - y;      // 128-row q-tile ids
  const int nA = y + 1;                 // tiles in segment A; nA + nB == 17
  const int b = bh >> 4, h = bh & 15;
  const size_t bS = (size_t)b * Sc;
  const int hd = h * 64;
  const int l31 = lane & 31, lhi = lane >> 5, l15 = lane & 15, l7 = lane & 7;

  // staging (identical to R15)
  const int krow = tid >> 3;
  const int kswz = (((tid & 7) ^ (krow & 7)) << 3);
  const int vrow = tid >> 4;
  const int vswz = (((tid & 15) ^ (vrow & 15)) << 3);
  const bf16* Kg0 = Kt  + (bS * QS) + (size_t)krow * QS + hd + kswz;
  const bf16* Vg0 = VTg + ((size_t)bh * 64 + vrow) * 2048 + vswz;

  // Q B-fragments: lane holds Q[d = dc*16 + 8*lhi + j][q = qbase + l31].
  bf16x8 qA0, qA1, qA2, qA3, qB0, qB1, qB2, qB3;
  {
    constexpr float QSC = 0.125f * L2E;
    const bf16* pA = Q + (bS + qtA * 128 + qw * 32 + l31) * QS + hd + lhi * 8;
    const bf16* pB = Q + (bS + qtB * 128 + qw * 32 + l31) * QS + hd + lhi * 8;
    qA0 = *(const bf16x8*)(pA);      qA1 = *(const bf16x8*)(pA + 16);
    qA2 = *(const bf16x8*)(pA + 32); qA3 = *(const bf16x8*)(pA + 48);
    qB0 = *(const bf16x8*)(pB);      qB1 = *(const bf16x8*)(pB + 16);
    qB2 = *(const bf16x8*)(pB + 32); qB3 = *(const bf16x8*)(pB + 48);
#pragma unroll
    for (int j = 0; j < 8; j++) {
      qA0[j] = (bf16)((float)qA0[j] * QSC); qA1[j] = (bf16)((float)qA1[j] * QSC);
      qA2[j] = (bf16)((float)qA2[j] * QSC); qA3[j] = (bf16)((float)qA3[j] * QSC);
      qB0[j] = (bf16)((float)qB0[j] * QSC); qB1[j] = (bf16)((float)qB1[j] * QSC);
      qB2[j] = (bf16)((float)qB2[j] * QSC); qB3[j] = (bf16)((float)qB3[j] * QSC);
    }
  }

  auto stage = [&](int bufi, int k0) {
    const bf16* kg = Kg0 + (size_t)k0 * QS;
    const bf16* vg = Vg0 + k0;
#pragma unroll
    for (int c = 0; c < 2; c++) {
      load_lds16(kg + (size_t)(c * 64) * QS, K_lds[bufi] + c * 4096 + tid * 8);
      load_lds16(vg + (size_t)(c * 32) * 2048, VT_lds[bufi] + c * 4096 + tid * 8);
    }
  };
  auto k0of = [&](int i) { return ((i >= nA) ? i - nA : i) * 128; };

  f32x16 oacc0 = zero16(), oacc1 = zero16();
  float lsum = 0.f;

  stage(0, 0);
  stage(1, k0of(1));

  for (int it = 0; it < 17; it++) {
    const int seg  = (it >= nA);
    const int kt   = seg ? (it - nA) : it;
    const int nkt  = seg ? (17 - nA) : nA;
    const int qt   = seg ? qtB : qtA;
    const int k0   = kt * 128;
    const int qbase = qt * 128 + qw * 32;
    const int bufc = it % 3;

    if (it == 16)                      asm volatile("s_waitcnt vmcnt(0)" ::: "memory");
    else if (it == nA || it == nA + 1) asm volatile("s_waitcnt vmcnt(8)" ::: "memory");
    else                               asm volatile("s_waitcnt vmcnt(4)" ::: "memory");
    __builtin_amdgcn_s_barrier();
    __builtin_amdgcn_sched_barrier(0);

    if (it + 2 < 17) stage((it + 2) % 3, k0of(it + 2));

    bf16x8 q0, q1, q2, q3;
    if (seg) { q0 = qB0; q1 = qB1; q2 = qB2; q3 = qB3; }
    else     { q0 = qA0; q1 = qA1; q2 = qA2; q3 = qA3; }

    const bf16* Kl = K_lds[bufc];
    const bf16* Vl = VT_lds[bufc];

    // QK^T: S^T for this wave's two 32-key blocks (kw half).
    f32x16 s0_ = zero16(), s1_ = zero16();
    __builtin_amdgcn_s_setprio(1);
    {
      const int kr0 = ((kw * 2 + 0) * 32 + l31) * 64;
      const int kr1 = ((kw * 2 + 1) * 32 + l31) * 64;
#pragma unroll
      for (int dc = 0; dc < 4; dc++) {
        const int so = (((2 * dc + lhi) ^ l7) << 3);
        bf16x8 qf = (dc == 0) ? q0 : (dc == 1) ? q1 : (dc == 2) ? q2 : q3;
        bf16x8 kf0 = *(const bf16x8*)(Kl + kr0 + so);
        s0_ = __builtin_amdgcn_mfma_f32_32x32x16_bf16(kf0, qf, s0_, 0, 0, 0);
        bf16x8 kf1 = *(const bf16x8*)(Kl + kr1 + so);
        s1_ = __builtin_amdgcn_mfma_f32_32x32x16_bf16(kf1, qf, s1_, 0, 0, 0);
      }
    }
    __builtin_amdgcn_s_setprio(0);

    if (kt == nkt - 1) {
      const int qq = qbase + l31;
      const int kb0 = k0 + kw * 64;
#pragma unroll
      for (int r = 0; r < 16; r++) {
        const int ky = kb0 + (r & 3) + 8 * (r >> 2) + 4 * lhi;
        if (ky > qq)      s0_[r] = NEG_BIG;
        if (ky + 32 > qq) s1_[r] = NEG_BIG;
      }
    }
#pragma unroll
    for (int r = 0; r < 16; r++) {
      const float p0 = fast_exp2(s0_[r]); s0_[r] = p0; lsum += p0;
      const float p1 = fast_exp2(s1_[r]); s1_[r] = p1; lsum += p1;
    }

    // PV: per (kb, f) 16-key B-frag -> 2 MFMAs (d-blocks).
#define PV_STEP(SACC, KB, F)                                                   \
    {                                                                          \
      uint32_t a0, a1, b0, b1;                                                 \
      asm("v_cvt_pk_bf16_f32 %0, %1, %2" : "=v"(a0)                            \
          : "v"(SACC[(F)*8 + 0]), "v"(SACC[(F)*8 + 1]));                       \
      asm("v_cvt_pk_bf16_f32 %0, %1, %2" : "=v"(a1)                            \
          : "v"(SACC[(F)*8 + 2]), "v"(SACC[(F)*8 + 3]));                       \
      asm("v_cvt_pk_bf16_f32 %0, %1, %2" : "=v"(b0)                            \
          : "v"(SACC[(F)*8 + 4]), "v"(SACC[(F)*8 + 5]));                       \
      asm("v_cvt_pk_bf16_f32 %0, %1, %2" : "=v"(b1)                            \
          : "v"(SACC[(F)*8 + 6]), "v"(SACC[(F)*8 + 7]));                       \
      asm("v_permlane32_swap_b32 %0, %1" : "+v"(a0), "+v"(b0));                \
      asm("v_permlane32_swap_b32 %0, %1" : "+v"(a1), "+v"(b1));                \
      union { uint32_t u[4]; bf16x8 v; } pk;                                   \
      pk.u[0] = a0; pk.u[1] = a1; pk.u[2] = b0; pk.u[3] = b1;                  \
      const int kc = kw * 8 + (KB) * 4 + (F) * 2;                              \
      const int vso = (((kc + lhi) ^ l15) << 3);                               \
      __builtin_amdgcn_s_setprio(1);                                           \
      { bf16x8 vf = *(const bf16x8*)(Vl + (l31) * 128 + vso);                  \
        oacc0 = __builtin_amdgcn_mfma_f32_32x32x16_bf16(vf, pk.v, oacc0, 0, 0, 0); } \
      { bf16x8 vf = *(const bf16x8*)(Vl + (32 + l31) * 128 + vso);             \
        oacc1 = __builtin_amdgcn_mfma_f32_32x32x16_bf16(vf, pk.v, oacc1, 0, 0, 0); } \
      __builtin_amdgcn_s_setprio(0);                                           \
    }
    PV_STEP(s0_, 0, 0)
    PV_STEP(s0_, 0, 1)
    PV_STEP(s1_, 1, 0)
    PV_STEP(s1_, 1, 1)
#undef PV_STEP

    // segment finalize: 4-phase exact-fit cross-kw combine via dead bufc LDS
    if (kt == nkt - 1) {
      float totw = lsum + __shfl_xor(lsum, 32, 64);
      asm volatile("s_waitcnt lgkmcnt(0)" ::: "memory");
      __builtin_amdgcn_s_barrier();           // all bufc reads complete
      float* Kf = (float*)(&K_lds[bufc][0]);  // 4096 floats (dead)
      float* Vf = (float*)(&VT_lds[bufc][0]); // 4096 floats (dead)
      float* slot = Kf + qw * 1024 + (lane << 4);
      // P1: kw=1 publishes oacc0; both publish tot
      if (lhi == 0) Vf[kw * 128 + qw * 32 + l31] = totw;
      if (kw == 1) {
#pragma unroll
        for (int g = 0; g < 4; g++)
          *(f32x4*)(slot + 4 * g) = f32x4{oacc0[4 * g], oacc0[4 * g + 1],
                                          oacc0[4 * g + 2], oacc0[4 * g + 3]};
      }
      asm volatile("s_waitcnt lgkmcnt(0)" ::: "memory");
      __builtin_amdgcn_s_barrier();
      __builtin_amdgcn_sched_barrier(0);
      const int q = qbase + l31;
      bf16* Op = O + (bS + q) * 1024 + hd + kw * 32 + 4 * lhi;
      const float ptot = Vf[(kw ^ 1) * 128 + qw * 32 + l31];
      const float inv = 1.0f / fmaxf(totw + ptot, 1e-37f);
      // P2: kw=0 combines oacc0, stores O rows d 0..31
      if (kw == 0) {
#pragma unroll
        for (int g = 0; g < 4; g++) {
          f32x4 po = *(const f32x4*)(slot + 4 * g);
          bf16x4 ov;
#pragma unroll
          for (int j = 0; j < 4; j++)
            ov[j] = (bf16)((oacc0[4 * g + j] + po[j]) * inv);
          *(bf16x4*)(Op + 8 * g) = ov;
        }
      }
      asm volatile("s_waitcnt lgkmcnt(0)" ::: "memory");
      __builtin_amdgcn_s_barrier();           // P2 reads done before overwrite
      // P3: kw=0 publishes oacc1 into the same slots
      if (kw == 0) {
#pragma unroll
        for (int g = 0; g < 4; g++)
          *(f32x4*)(slot + 4 * g) = f32x4{oacc1[4 * g], oacc1[4 * g + 1],
                                          oacc1[4 * g + 2], oacc1[4 * g + 3]};
      }
      asm volatile("s_waitcnt lgkmcnt(0)" ::: "memory");
      __builtin_amdgcn_s_barrier();
      __builtin_amdgcn_sched_barrier(0);
      // P4: kw=1 combines oacc1, stores O rows d 32..63
      if (kw == 1) {
#pragma unroll
        for (int g = 0; g < 4; g++) {
          f32x4 po = *(const f32x4*)(slot + 4 * g);
          bf16x4 ov;
#pragma unroll
          for (int j = 0; j < 4; j++)
            ov[j] = (bf16)((oacc1[4 * g + j] + po[j]) * inv);
          *(bf16x4*)(Op + 8 * g) = ov;
        }
      }
      oacc0 = zero16(); oacc1 = zero16();
      lsum = 0.f;
    }
  }
}

// ---------------------------------------------------------------------------
extern "C" void kernel_launch(void* const* d_in, const int* in_sizes, int n_in,
                              void* d_out, int out_size, void* d_ws, size_t ws_size,
                              hipStream_t stream) {
  (void)in_sizes; (void)n_in; (void)out_size; (void)ws_size;
  const float* hs   = (const float*)d_in[0];
  const float* Wqkv = (const float*)d_in[1];
  const float* bqkv = (const float*)d_in[2];
  const float* Wqa  = (const float*)d_in[3];
  const float* bqa  = (const float*)d_in[4];
  const float* Wka  = (const float*)d_in[5];
  const float* bka  = (const float*)d_in[6];
  const float* Wd   = (const float*)d_in[7];
  const float* bd   = (const float*)d_in[8];
  float* out = (float*)d_out;

  const size_t TH = (size_t)Tc * Hc;            // 4,194,304
  bf16* dob   = (bf16*)d_out;
  bf16* hsb   = dob;
  bf16* wqkvb = dob + TH;
  bf16* Ah    = dob;
  bf16* VTg   = dob + TH;
  bf16* ws     = (bf16*)d_ws;
  bf16* qkv    = ws;
  bf16* qaka   = ws;
  bf16* oh     = ws + 2 * TH;
  bf16* wqakab = ws + 3 * TH;
  bf16* wdb    = wqakab + 2 * 1024 * 1024;
  float* bqaka = (float*)(wdb + 1024 * 1024);

  convert_all<<<dim3(5121), 256, 0, stream>>>(hs, Wqkv, Wqa, Wka, Wd, bqa, bka,
                                              hsb, wqkvb, wqakab, wdb, bqaka);

  gemm128<bf16><<<dim3(24, 32), 256, 0, stream>>>(hsb, wqkvb, bqkv, qkv, Tc, 3 * Hc, Hc);
  window_attn<<<dim3(Tc * NHc / 16), 256, 0, stream>>>(qkv, Ah, VTg);
  gemm128<bf16><<<dim3(16, 32), 256, 0, stream>>>(Ah, wqakab, bqaka, qaka, Tc, 2 * Hc, Hc);
  // flash: 256 blocks x 512 thr, q=128/block, 17 tiles, 32x32 frags (R22)
  flash_attn<<<dim3(Bc * NHc, 8), 512, 0, stream>>>(qaka, qaka + Hc, VTg, oh);
  // final projection: 128x64 tiles, 512 blocks = 2/CU
  gemm12864<float><<<dim3(16, 32), 256, 0, stream>>>(oh, wdb, bd, out, Tc, Hc, Hc);
}